// Round 12
// baseline (196.513 us; speedup 1.0000x reference)
//
#include <hip/hip_runtime.h>
#include <hip/hip_fp16.h>

#define BATCH 4096
#define EPS 1e-5f

typedef __half h16;
typedef float f32x2 __attribute__((ext_vector_type(2)));
typedef _Float16 h16x2 __attribute__((ext_vector_type(2)));
typedef unsigned int u32;

union H8 { float4 f4; h16 h[8]; __half2 h2[4]; };
union U4 { float4 f4; u32 u[4]; };
union H2U { float f; __half2 h2; h16x2 hv; u32 u; };

__device__ __forceinline__ float tanh_fast(float x){
  float e = __expf(2.0f*x);
  return 1.0f - 2.0f*__builtin_amdgcn_rcpf(e + 1.0f);
}

__device__ __forceinline__ float wred(float v){
  #pragma unroll
  for (int off=32; off; off>>=1) v += __shfl_xor(v, off);
  return v;
}

__device__ __forceinline__ float dot2(u32 a, u32 b, float c){
#if __has_builtin(__builtin_amdgcn_fdot2)
  H2U ua, ub; ua.u = a; ub.u = b;
  return __builtin_amdgcn_fdot2(ua.hv, ub.hv, c, false);
#else
  H2U ua, ub; ua.u = a; ub.u = b;
  float2 fa = __half22float2(ua.h2);
  float2 fb = __half22float2(ub.h2);
  return fmaf(fa.y, fb.y, fmaf(fa.x, fb.x, c));
#endif
}

// ---------------- transpose: ms[4096][6000] f32 -> msT[6000][4096] f16 ----------------
__global__ __launch_bounds__(256) void k_transpose(const float* __restrict__ ms, h16* __restrict__ msT){
  __shared__ float tile[64][65];
  int tc = blockIdx.x * 64;
  int tb = blockIdx.y * 64;
  int tx = threadIdx.x & 63;
  int ty = threadIdx.x >> 6;
  #pragma unroll
  for (int k=0;k<16;++k){
    int r = ty + k*4;
    int c = tc + tx;
    if (c < 6000) tile[r][tx] = ms[(size_t)(tb + r)*6000 + c];
  }
  __syncthreads();
  #pragma unroll
  for (int k=0;k<16;++k){
    int r = ty + k*4;
    int c = tc + r;
    if (c < 6000) msT[(size_t)c*BATCH + tb + tx] = __float2half(tile[tx][r]);
  }
}

// ---------------- pass A: level-1 linear+tanh -> H1p[pair][b] u32 + stats ----------------
// grid (8 bc, 512 s), block 64; thread handles 8 batch elems
__global__ __launch_bounds__(64,2) void k_statsA(const h16* __restrict__ msT, const int* __restrict__ gidx,
    const float* __restrict__ W1, const float* __restrict__ b1,
    u32* __restrict__ H1p, float* __restrict__ part1){
  const int s = blockIdx.y;
  const int bc = blockIdx.x;           // 8
  const int lane = threadIdx.x;
  const int b0 = bc*512 + lane*8;
  const float* Wp = W1 + s*320;
  f32x2 acc[20][4];
  #pragma unroll
  for (int o=0;o<20;++o){
    float bv = b1[s*20+o];
    #pragma unroll
    for (int k=0;k<4;++k) acc[o][k] = (f32x2){bv,bv};
  }
  #pragma unroll 4
  for (int g=0; g<16; ++g){
    const int row = gidx[s*16+g]*BATCH;        // s block-uniform -> SGPR
    H8 u; u.f4 = *reinterpret_cast<const float4*>(msT + row + b0);
    f32x2 x[4];
    #pragma unroll
    for (int k=0;k<4;++k){
      float2 f = __half22float2(u.h2[k]);
      x[k] = (f32x2){f.x, f.y};
    }
    #pragma unroll
    for (int o=0;o<20;++o){
      float wv = Wp[o*16+g];
      f32x2 w2 = (f32x2){wv,wv};
      #pragma unroll
      for (int k=0;k<4;++k) acc[o][k] = __builtin_elementwise_fma(x[k], w2, acc[o][k]);
    }
  }
  #pragma unroll
  for (int op=0;op<10;++op){
    const int oA = 2*op, oB = 2*op+1;
    float hA[8], hB[8];
    #pragma unroll
    for (int k=0;k<4;++k){
      hA[2*k]   = tanh_fast(acc[oA][k].x);
      hA[2*k+1] = tanh_fast(acc[oA][k].y);
      hB[2*k]   = tanh_fast(acc[oB][k].x);
      hB[2*k+1] = tanh_fast(acc[oB][k].y);
    }
    U4 v0, v1;
    #pragma unroll
    for (int k=0;k<4;++k){
      H2U a; a.h2 = __halves2half2(__float2half(hA[k]),   __float2half(hB[k]));   v0.u[k] = a.u;
      H2U b; b.h2 = __halves2half2(__float2half(hA[k+4]), __float2half(hB[k+4])); v1.u[k] = b.u;
    }
    u32* dst = H1p + (size_t)(s*10+op)*BATCH + b0;
    *reinterpret_cast<float4*>(dst)     = v0.f4;
    *reinterpret_cast<float4*>(dst + 4) = v1.f4;
    float SA = ((hA[0]+hA[1])+(hA[2]+hA[3])) + ((hA[4]+hA[5])+(hA[6]+hA[7]));
    float QA = ((hA[0]*hA[0]+hA[1]*hA[1])+(hA[2]*hA[2]+hA[3]*hA[3]))
             + ((hA[4]*hA[4]+hA[5]*hA[5])+(hA[6]*hA[6]+hA[7]*hA[7]));
    float SB = ((hB[0]+hB[1])+(hB[2]+hB[3])) + ((hB[4]+hB[5])+(hB[6]+hB[7]));
    float QB = ((hB[0]*hB[0]+hB[1]*hB[1])+(hB[2]*hB[2]+hB[3]*hB[3]))
             + ((hB[4]*hB[4]+hB[5]*hB[5])+(hB[6]*hB[6]+hB[7]*hB[7]));
    SA = wred(SA); QA = wred(QA); SB = wred(SB); QB = wred(QB);
    if (lane==0){
      part1[((s*20+oA)*2  )*8 + bc] = SA;
      part1[((s*20+oA)*2+1)*8 + bc] = QA;
      part1[((s*20+oB)*2  )*8 + bc] = SB;
      part1[((s*20+oB)*2+1)*8 + bc] = QB;
    }
  }
}

// ---------------- fold level-1 BN into W2: packed f16 channel-pairs [i2][j] ----------------
__global__ __launch_bounds__(256) void k_fold2(const float* __restrict__ W, const float* __restrict__ bb,
    const float* __restrict__ g, const float* __restrict__ beta,
    const float* __restrict__ part, u32* __restrict__ W2h, float* __restrict__ bf){
  const int p = blockIdx.x;
  const int tid = threadIdx.x;
  __shared__ float aL[160], cL[160];
  for (int t = tid; t < 160; t += 256){
    int ch = p*160 + t;
    float S=0.f, Q=0.f;
    for (int bc=0; bc<8; ++bc){ S += part[(ch*2)*8 + bc]; Q += part[(ch*2+1)*8 + bc]; }
    float mu  = S * (1.0f/BATCH);
    float var = Q * (1.0f/BATCH) - mu*mu;
    float a = g[ch] * rsqrtf(var + EPS);
    aL[t] = a;
    cL[t] = beta[ch] - a*mu;
  }
  __syncthreads();
  const int NW = 160*24;
  for (int e = tid; e < 80*24; e += 256){
    int i2 = e / 24, j = e % 24;
    float w0 = W[p*NW + j*160 + 2*i2    ] * aL[2*i2];
    float w1 = W[p*NW + j*160 + 2*i2 + 1] * aL[2*i2+1];
    H2U u; u.h2 = __halves2half2(__float2half(w0), __float2half(w1));
    W2h[p*1920 + e] = u.u;
  }
  if (tid < 24){
    float sv = bb[p*24 + tid];
    for (int i=0;i<160;++i) sv = fmaf(W[p*NW + tid*160 + i], cL[i], sv);
    bf[p*24 + tid] = sv;
  }
}

// ---------------- pass B: H1p x W2h (fdot2) -> H2[p][b][24] + stats ----------------
// grid (16 bc, 64 p), block 256 = 4 waves (all same p); 1 batch elem per thread.
// All 80 H1p row-loads issued up front (max MLP); 128-VGPR budget via launch_bounds.
__global__ __launch_bounds__(256,4) void k_passB(const u32* __restrict__ H1p,
    const u32* __restrict__ W2h, const float* __restrict__ b2f,
    h16* __restrict__ H2, float* __restrict__ part2){
  const int p = blockIdx.y;
  const int bc = blockIdx.x;           // 16
  const int tid = threadIdx.x;
  const int wv = tid >> 6;             // 0..3
  const int lane = tid & 63;
  const int b = bc*256 + tid;
  const int bcw = bc*4 + wv;           // 64 batch chunks
  const u32* __restrict__ hbase = H1p + (size_t)p*80*BATCH + b;   // 80 pair-rows per p
  u32 xr[80];
  #pragma unroll
  for (int r=0;r<80;++r) xr[r] = hbase[(size_t)r*BATCH];
  float acc[24];
  #pragma unroll
  for (int j=0;j<24;++j) acc[j] = b2f[p*24+j];
  const u32* __restrict__ wp = W2h + p*1920;   // [r][j] packed pairs, r = c*10+op
  #pragma unroll
  for (int r=0;r<80;++r){
    const u32 xa = xr[r];
    const u32* wj = wp + r*24;
    #pragma unroll
    for (int j=0;j<24;++j) acc[j] = dot2(xa, wj[j], acc[j]);
  }
  float v[24];
  #pragma unroll
  for (int j=0;j<24;++j) v[j] = tanh_fast(acc[j]);
  {
    h16* dst = H2 + ((size_t)p*BATCH + b)*24;
    #pragma unroll
    for (int t=0;t<3;++t){
      H8 u;
      #pragma unroll
      for (int k=0;k<8;++k) u.h[k] = __float2half(v[t*8+k]);
      *reinterpret_cast<float4*>(dst + t*8) = u.f4;
    }
  }
  #pragma unroll
  for (int j=0;j<24;++j){
    float S = wred(v[j]);
    float Q = wred(v[j]*v[j]);
    if (lane==0){
      part2[((p*24+j)*2  )*64 + bcw] = S;
      part2[((p*24+j)*2+1)*64 + bcw] = Q;
    }
  }
}

// ---------------- pass C: inline-BN(level2) + level-3 -> H3[b][256] + stats ----------------
// grid (64 bc, 8 q), block 512 (8 waves x 4 outputs)
__global__ __launch_bounds__(512) void k_passC(const h16* __restrict__ H2, const float* __restrict__ part2,
    const float* __restrict__ g2, const float* __restrict__ beta2,
    const float* __restrict__ W3, const float* __restrict__ b3,
    h16* __restrict__ H3, float* __restrict__ part3){
  const int q = blockIdx.y;
  const int bc = blockIdx.x;           // 64
  const int tid = threadIdx.x;
  const int wv = tid >> 6;
  const int lane = tid & 63;
  __shared__ float aL[192], cL[192];
  for (int t = tid; t < 192; t += 512){
    int ch = q*192 + t;
    float S=0.f, Q=0.f;
    for (int c=0;c<64;++c){ S += part2[(ch*2)*64 + c]; Q += part2[(ch*2+1)*64 + c]; }
    float mu  = S * (1.0f/BATCH);
    float var = Q * (1.0f/BATCH) - mu*mu;
    float a = g2[ch] * rsqrtf(var + EPS);
    aL[t] = a; cL[t] = beta2[ch] - a*mu;
  }
  __syncthreads();
  const int b = bc*64 + lane;
  const int jb = wv*4;
  float acc[4];
  #pragma unroll
  for (int j=0;j<4;++j) acc[j] = b3[q*32 + jb + j];
  for (int c2=0;c2<8;++c2){
    const h16* src = H2 + ((size_t)(q*8+c2)*BATCH + b)*24;
    float xn[24];
    #pragma unroll
    for (int t=0;t<3;++t){
      H8 u; u.f4 = *reinterpret_cast<const float4*>(src + t*8);
      #pragma unroll
      for (int i=0;i<8;++i){
        int ci = c2*24 + t*8 + i;
        xn[t*8+i] = fmaf(aL[ci], __half2float(u.h[i]), cL[ci]);
      }
    }
    #pragma unroll
    for (int j=0;j<4;++j){
      const float* wr = W3 + q*6144 + (jb+j)*192 + c2*24;
      #pragma unroll
      for (int i=0;i<24;++i) acc[j] = fmaf(xn[i], wr[i], acc[j]);
    }
  }
  #pragma unroll
  for (int j=0;j<4;++j) acc[j] = tanh_fast(acc[j]);
  {
    h16* dst = H3 + (size_t)b*256 + q*32 + jb;
    H2U u0,u1;
    u0.h2 = __halves2half2(__float2half(acc[0]), __float2half(acc[1]));
    u1.h2 = __halves2half2(__float2half(acc[2]), __float2half(acc[3]));
    float2 vv; vv.x = u0.f; vv.y = u1.f;
    *reinterpret_cast<float2*>(dst) = vv;
  }
  #pragma unroll
  for (int j=0;j<4;++j){
    float S = wred(acc[j]);
    float Q = wred(acc[j]*acc[j]);
    if (lane==0){
      part3[((q*32+jb+j)*2  )*64 + bc] = S;
      part3[((q*32+jb+j)*2+1)*64 + bc] = Q;
    }
  }
}

// ---------------- pass D: inline-BN(level3) + root -> Hr f32 [b][64] + stats ----------------
// grid (64 bc, 8 jg), block 256 = 4 waves; wave wv handles channels [wv*64, wv*64+64); LDS combine
__global__ __launch_bounds__(256) void k_passD(const h16* __restrict__ H3, const float* __restrict__ part3,
    const float* __restrict__ g3, const float* __restrict__ beta3,
    const float* __restrict__ Wr, const float* __restrict__ br,
    float* __restrict__ Hr, float* __restrict__ partR){
  const int bc = blockIdx.x;           // 64
  const int jb = blockIdx.y * 8;       // 8 groups
  const int tid = threadIdx.x;
  const int wv = tid >> 6;
  const int lane = tid & 63;
  __shared__ float aL[256], cL[256];
  __shared__ float lacc[4][64][9];
  {
    float S=0.f, Q=0.f;
    for (int c=0;c<64;++c){ S += part3[(tid*2)*64 + c]; Q += part3[(tid*2+1)*64 + c]; }
    float mu  = S * (1.0f/BATCH);
    float var = Q * (1.0f/BATCH) - mu*mu;
    float a = g3[tid] * rsqrtf(var + EPS);
    aL[tid] = a; cL[tid] = beta3[tid] - a*mu;
  }
  __syncthreads();
  const int b = bc*64 + lane;
  float acc[8];
  #pragma unroll
  for (int j=0;j<8;++j) acc[j] = 0.f;
  const h16* src = H3 + (size_t)b*256 + wv*64;
  #pragma unroll
  for (int kk=0; kk<8; ++kk){
    const int sl = wv*8 + kk;
    H8 u; u.f4 = *reinterpret_cast<const float4*>(src + kk*8);
    float xn[8];
    #pragma unroll
    for (int i=0;i<8;++i){
      int ci = sl*8+i;
      xn[i] = fmaf(aL[ci], __half2float(u.h[i]), cL[ci]);
    }
    #pragma unroll
    for (int j=0;j<8;++j){
      const float* wr = Wr + (jb+j)*256 + sl*8;
      #pragma unroll
      for (int i=0;i<8;++i) acc[j] = fmaf(xn[i], wr[i], acc[j]);
    }
  }
  #pragma unroll
  for (int j=0;j<8;++j) lacc[wv][lane][j] = acc[j];
  __syncthreads();
  #pragma unroll
  for (int k=0;k<2;++k){
    const int j = k*4 + wv;
    float v = br[jb+j] + (lacc[0][lane][j] + lacc[1][lane][j]) + (lacc[2][lane][j] + lacc[3][lane][j]);
    v = tanh_fast(v);
    Hr[(size_t)b*64 + jb + j] = v;
    float S = wred(v);
    float Q = wred(v*v);
    if (lane==0){
      partR[((jb+j)*2  )*64 + bc] = S;
      partR[((jb+j)*2+1)*64 + bc] = Q;
    }
  }
}

// ---------------- final BN on root output ----------------
__global__ __launch_bounds__(256) void k_final(const float* __restrict__ Hr, const float* __restrict__ partR,
    const float* __restrict__ gr, const float* __restrict__ betar, float* __restrict__ out){
  __shared__ float aL[64], cL[64];
  const int tid = threadIdx.x;
  if (tid < 64){
    float S=0.f, Q=0.f;
    for (int bc=0; bc<64; ++bc){ S += partR[(tid*2)*64 + bc]; Q += partR[(tid*2+1)*64 + bc]; }
    float mu  = S * (1.0f/BATCH);
    float var = Q * (1.0f/BATCH) - mu*mu;
    float a = gr[tid] * rsqrtf(var + EPS);
    aL[tid] = a; cL[tid] = betar[tid] - a*mu;
  }
  __syncthreads();
  const int i4 = blockIdx.x*256 + tid;       // 65536 float4s
  float4 v = *reinterpret_cast<const float4*>(Hr + (size_t)i4*4);
  int o = (i4*4)&63;
  float4 r;
  r.x = aL[o  ]*v.x + cL[o  ];
  r.y = aL[o+1]*v.y + cL[o+1];
  r.z = aL[o+2]*v.z + cL[o+2];
  r.w = aL[o+3]*v.w + cL[o+3];
  *reinterpret_cast<float4*>(out + (size_t)i4*4) = r;
}

extern "C" void kernel_launch(void* const* d_in, const int* in_sizes, int n_in,
                              void* d_out, int out_size, void* d_ws, size_t ws_size,
                              hipStream_t stream) {
  const float* ms    = (const float*)d_in[0];
  const int*   gidx  = (const int*)  d_in[1];
  const float* W1    = (const float*)d_in[2];
  const float* b1    = (const float*)d_in[3];
  const float* g1    = (const float*)d_in[4];
  const float* beta1 = (const float*)d_in[5];
  const float* W2    = (const float*)d_in[6];
  const float* b2    = (const float*)d_in[7];
  const float* g2    = (const float*)d_in[8];
  const float* beta2 = (const float*)d_in[9];
  const float* W3    = (const float*)d_in[10];
  const float* b3    = (const float*)d_in[11];
  const float* g3    = (const float*)d_in[12];
  const float* beta3 = (const float*)d_in[13];
  const float* Wr    = (const float*)d_in[14];
  const float* br    = (const float*)d_in[15];
  const float* gr    = (const float*)d_in[16];
  const float* betar = (const float*)d_in[17];
  float* out = (float*)d_out;

  char* w = (char*)d_ws;
  size_t off = 0;
  auto take = [&](size_t bytes)->char*{
    char* p = w + off;
    off = (off + bytes + 255) & ~(size_t)255;
    return p;
  };
  h16*   msT    = (h16*)  take((size_t)6000*BATCH*2);
  u32*   H1p    = (u32*)  take((size_t)5120*BATCH*4);
  h16*   H2     = (h16*)  take((size_t)64*BATCH*24*2);
  h16*   H3     = (h16*)  take((size_t)BATCH*256*2);
  float* Hr     = (float*)take((size_t)BATCH*64*4);
  float* part1  = (float*)take((size_t)10240*2*8*4);
  float* part2  = (float*)take((size_t)1536*2*64*4);
  float* part3  = (float*)take((size_t)256*2*64*4);
  float* partR  = (float*)take((size_t)64*2*64*4);
  u32*   W2h    = (u32*)  take((size_t)64*1920*4);
  float* b2f    = (float*)take((size_t)64*24*4);
  if (off > ws_size) return;

  k_transpose<<<dim3(94,64), 256, 0, stream>>>(ms, msT);
  k_statsA<<<dim3(8,512), 64, 0, stream>>>(msT, gidx, W1, b1, H1p, part1);
  k_fold2<<<64, 256, 0, stream>>>(W2, b2, g1, beta1, part1, W2h, b2f);
  k_passB<<<dim3(16,64), 256, 0, stream>>>(H1p, W2h, b2f, H2, part2);
  k_passC<<<dim3(64,8), 512, 0, stream>>>(H2, part2, g2, beta2, W3, b3, H3, part3);
  k_passD<<<dim3(64,8), 256, 0, stream>>>(H3, part3, g3, beta3, Wr, br, Hr, partR);
  k_final<<<256, 256, 0, stream>>>(Hr, partR, gr, betar, out);
}

// Round 13
// 181.321 us; speedup vs baseline: 1.0838x; 1.0838x over previous
//
#include <hip/hip_runtime.h>
#include <hip/hip_fp16.h>

#define BATCH 4096
#define EPS 1e-5f

typedef __half h16;
typedef float f32x2 __attribute__((ext_vector_type(2)));
typedef _Float16 h16x2 __attribute__((ext_vector_type(2)));
typedef unsigned int u32;

union H8 { float4 f4; h16 h[8]; __half2 h2[4]; };
union U4 { float4 f4; u32 u[4]; };
union H2U { float f; __half2 h2; h16x2 hv; u32 u; };

__device__ __forceinline__ float tanh_fast(float x){
  float e = __expf(2.0f*x);
  return 1.0f - 2.0f*__builtin_amdgcn_rcpf(e + 1.0f);
}

__device__ __forceinline__ float wred(float v){
  #pragma unroll
  for (int off=32; off; off>>=1) v += __shfl_xor(v, off);
  return v;
}

__device__ __forceinline__ float dot2(u32 a, u32 b, float c){
#if __has_builtin(__builtin_amdgcn_fdot2)
  H2U ua, ub; ua.u = a; ub.u = b;
  return __builtin_amdgcn_fdot2(ua.hv, ub.hv, c, false);
#else
  H2U ua, ub; ua.u = a; ub.u = b;
  float2 fa = __half22float2(ua.h2);
  float2 fb = __half22float2(ub.h2);
  return fmaf(fa.y, fb.y, fmaf(fa.x, fb.x, c));
#endif
}

// ---------------- transpose: ms[4096][6000] f32 -> msT[6000][4096] f16 ----------------
__global__ __launch_bounds__(256) void k_transpose(const float* __restrict__ ms, h16* __restrict__ msT){
  __shared__ float tile[64][65];
  int tc = blockIdx.x * 64;
  int tb = blockIdx.y * 64;
  int tx = threadIdx.x & 63;
  int ty = threadIdx.x >> 6;
  #pragma unroll
  for (int k=0;k<16;++k){
    int r = ty + k*4;
    int c = tc + tx;
    if (c < 6000) tile[r][tx] = ms[(size_t)(tb + r)*6000 + c];
  }
  __syncthreads();
  #pragma unroll
  for (int k=0;k<16;++k){
    int r = ty + k*4;
    int c = tc + r;
    if (c < 6000) msT[(size_t)c*BATCH + tb + tx] = __float2half(tile[tx][r]);
  }
}

// ---------------- pass A: level-1 linear+tanh -> H1p[pair][b] u32 + stats ----------------
// grid (8 bc, 512 s), block 64; thread handles 8 batch elems
__global__ __launch_bounds__(64,2) void k_statsA(const h16* __restrict__ msT, const int* __restrict__ gidx,
    const float* __restrict__ W1, const float* __restrict__ b1,
    u32* __restrict__ H1p, float* __restrict__ part1){
  const int s = blockIdx.y;
  const int bc = blockIdx.x;           // 8
  const int lane = threadIdx.x;
  const int b0 = bc*512 + lane*8;
  const float* Wp = W1 + s*320;
  f32x2 acc[20][4];
  #pragma unroll
  for (int o=0;o<20;++o){
    float bv = b1[s*20+o];
    #pragma unroll
    for (int k=0;k<4;++k) acc[o][k] = (f32x2){bv,bv};
  }
  #pragma unroll 4
  for (int g=0; g<16; ++g){
    const int row = gidx[s*16+g]*BATCH;        // s block-uniform -> SGPR
    H8 u; u.f4 = *reinterpret_cast<const float4*>(msT + row + b0);
    f32x2 x[4];
    #pragma unroll
    for (int k=0;k<4;++k){
      float2 f = __half22float2(u.h2[k]);
      x[k] = (f32x2){f.x, f.y};
    }
    #pragma unroll
    for (int o=0;o<20;++o){
      float wv = Wp[o*16+g];
      f32x2 w2 = (f32x2){wv,wv};
      #pragma unroll
      for (int k=0;k<4;++k) acc[o][k] = __builtin_elementwise_fma(x[k], w2, acc[o][k]);
    }
  }
  #pragma unroll
  for (int op=0;op<10;++op){
    const int oA = 2*op, oB = 2*op+1;
    float hA[8], hB[8];
    #pragma unroll
    for (int k=0;k<4;++k){
      hA[2*k]   = tanh_fast(acc[oA][k].x);
      hA[2*k+1] = tanh_fast(acc[oA][k].y);
      hB[2*k]   = tanh_fast(acc[oB][k].x);
      hB[2*k+1] = tanh_fast(acc[oB][k].y);
    }
    U4 v0, v1;
    #pragma unroll
    for (int k=0;k<4;++k){
      H2U a; a.h2 = __halves2half2(__float2half(hA[k]),   __float2half(hB[k]));   v0.u[k] = a.u;
      H2U b; b.h2 = __halves2half2(__float2half(hA[k+4]), __float2half(hB[k+4])); v1.u[k] = b.u;
    }
    u32* dst = H1p + (size_t)(s*10+op)*BATCH + b0;
    *reinterpret_cast<float4*>(dst)     = v0.f4;
    *reinterpret_cast<float4*>(dst + 4) = v1.f4;
    float SA = ((hA[0]+hA[1])+(hA[2]+hA[3])) + ((hA[4]+hA[5])+(hA[6]+hA[7]));
    float QA = ((hA[0]*hA[0]+hA[1]*hA[1])+(hA[2]*hA[2]+hA[3]*hA[3]))
             + ((hA[4]*hA[4]+hA[5]*hA[5])+(hA[6]*hA[6]+hA[7]*hA[7]));
    float SB = ((hB[0]+hB[1])+(hB[2]+hB[3])) + ((hB[4]+hB[5])+(hB[6]+hB[7]));
    float QB = ((hB[0]*hB[0]+hB[1]*hB[1])+(hB[2]*hB[2]+hB[3]*hB[3]))
             + ((hB[4]*hB[4]+hB[5]*hB[5])+(hB[6]*hB[6]+hB[7]*hB[7]));
    SA = wred(SA); QA = wred(QA); SB = wred(SB); QB = wred(QB);
    if (lane==0){
      part1[((s*20+oA)*2  )*8 + bc] = SA;
      part1[((s*20+oA)*2+1)*8 + bc] = QA;
      part1[((s*20+oB)*2  )*8 + bc] = SB;
      part1[((s*20+oB)*2+1)*8 + bc] = QB;
    }
  }
}

// ---------------- fold level-1 BN into W2: packed f16 channel-pairs [i2][j] ----------------
__global__ __launch_bounds__(256) void k_fold2(const float* __restrict__ W, const float* __restrict__ bb,
    const float* __restrict__ g, const float* __restrict__ beta,
    const float* __restrict__ part, u32* __restrict__ W2h, float* __restrict__ bf){
  const int p = blockIdx.x;
  const int tid = threadIdx.x;
  __shared__ float aL[160], cL[160];
  for (int t = tid; t < 160; t += 256){
    int ch = p*160 + t;
    float S=0.f, Q=0.f;
    for (int bc=0; bc<8; ++bc){ S += part[(ch*2)*8 + bc]; Q += part[(ch*2+1)*8 + bc]; }
    float mu  = S * (1.0f/BATCH);
    float var = Q * (1.0f/BATCH) - mu*mu;
    float a = g[ch] * rsqrtf(var + EPS);
    aL[t] = a;
    cL[t] = beta[ch] - a*mu;
  }
  __syncthreads();
  const int NW = 160*24;
  for (int e = tid; e < 80*24; e += 256){
    int i2 = e / 24, j = e % 24;
    float w0 = W[p*NW + j*160 + 2*i2    ] * aL[2*i2];
    float w1 = W[p*NW + j*160 + 2*i2 + 1] * aL[2*i2+1];
    H2U u; u.h2 = __halves2half2(__float2half(w0), __float2half(w1));
    W2h[p*1920 + e] = u.u;
  }
  if (tid < 24){
    float sv = bb[p*24 + tid];
    for (int i=0;i<160;++i) sv = fmaf(W[p*NW + tid*160 + i], cL[i], sv);
    bf[p*24 + tid] = sv;
  }
}

// ---------------- pass B: H1p x W2h (fdot2) -> H2[p][b][24]  (NO stats) ----------------
// grid (8 bc, 64 p), block 512 = 8 waves (all same p); 1 batch elem per thread
__global__ __launch_bounds__(512) void k_passB(const u32* __restrict__ H1p,
    const u32* __restrict__ W2h, const float* __restrict__ b2f,
    h16* __restrict__ H2){
  const int p = blockIdx.y;
  const int bc = blockIdx.x;           // 8
  const int tid = threadIdx.x;
  const int b = bc*512 + tid;
  float acc[24];
  #pragma unroll
  for (int j=0;j<24;++j) acc[j] = b2f[p*24+j];
  const u32* __restrict__ wp = W2h + p*1920;                      // [r][j] packed pairs
  const u32* __restrict__ hbase = H1p + (size_t)p*80*BATCH + b;   // 80 pair-rows per p
  u32 buf[2][10];
  #pragma unroll
  for (int op=0;op<10;++op) buf[0][op] = hbase[(size_t)op*BATCH];
  #pragma unroll
  for (int c=0;c<8;++c){
    if (c < 7){
      #pragma unroll
      for (int op=0;op<10;++op)
        buf[(c+1)&1][op] = hbase[(size_t)((c+1)*10+op)*BATCH];
    }
    const u32* wj0 = wp + c*240;
    #pragma unroll
    for (int op=0;op<10;++op){
      const u32 xa = buf[c&1][op];
      const u32* wj = wj0 + op*24;
      #pragma unroll
      for (int j=0;j<24;++j){
        acc[j] = dot2(xa, wj[j], acc[j]);
      }
    }
  }
  float v[24];
  #pragma unroll
  for (int j=0;j<24;++j) v[j] = tanh_fast(acc[j]);
  h16* dst = H2 + ((size_t)p*BATCH + b)*24;
  #pragma unroll
  for (int t=0;t<3;++t){
    H8 u;
    #pragma unroll
    for (int k=0;k<8;++k) u.h[k] = __float2half(v[t*8+k]);
    *reinterpret_cast<float4*>(dst + t*8) = u.f4;
  }
}

// ---------------- stats over H2 -> part2 [ch*2+{0,1}][4 chunks] ----------------
// grid (4 bc, 64 p), block 256; thread accumulates 4 rows of 24 ch
__global__ __launch_bounds__(256) void k_stats2(const h16* __restrict__ H2, float* __restrict__ part2){
  const int p = blockIdx.y;
  const int bc = blockIdx.x;           // 4
  const int tid = threadIdx.x;
  const int wv = tid >> 6;
  const int lane = tid & 63;
  float S[24], Q[24];
  #pragma unroll
  for (int j=0;j<24;++j){ S[j]=0.f; Q[j]=0.f; }
  const h16* base = H2 + ((size_t)p*BATCH + bc*1024 + tid)*24;
  for (int it=0; it<4; ++it){
    const h16* src = base + (size_t)it*256*24;
    #pragma unroll
    for (int t=0;t<3;++t){
      H8 u; u.f4 = *reinterpret_cast<const float4*>(src + t*8);
      #pragma unroll
      for (int i=0;i<8;++i){
        float v = __half2float(u.h[i]);
        S[t*8+i] += v;
        Q[t*8+i] = fmaf(v, v, Q[t*8+i]);
      }
    }
  }
  __shared__ float red[2][4][24];
  #pragma unroll
  for (int j=0;j<24;++j){
    float s = wred(S[j]);
    float q = wred(Q[j]);
    if (lane==0){ red[0][wv][j] = s; red[1][wv][j] = q; }
  }
  __syncthreads();
  if (tid < 24){
    float s = (red[0][0][tid]+red[0][1][tid]) + (red[0][2][tid]+red[0][3][tid]);
    float q = (red[1][0][tid]+red[1][1][tid]) + (red[1][2][tid]+red[1][3][tid]);
    const int ch = p*24 + tid;
    part2[(ch*2  )*4 + bc] = s;
    part2[(ch*2+1)*4 + bc] = q;
  }
}

// ---------------- pass C: inline-BN(level2) + level-3 -> H3[b][256] + stats ----------------
// grid (64 bc, 8 q), block 512 (8 waves x 4 outputs)
__global__ __launch_bounds__(512) void k_passC(const h16* __restrict__ H2, const float* __restrict__ part2,
    const float* __restrict__ g2, const float* __restrict__ beta2,
    const float* __restrict__ W3, const float* __restrict__ b3,
    h16* __restrict__ H3, float* __restrict__ part3){
  const int q = blockIdx.y;
  const int bc = blockIdx.x;           // 64
  const int tid = threadIdx.x;
  const int wv = tid >> 6;
  const int lane = tid & 63;
  __shared__ float aL[192], cL[192];
  for (int t = tid; t < 192; t += 512){
    int ch = q*192 + t;
    float S=0.f, Q=0.f;
    #pragma unroll
    for (int c=0;c<4;++c){ S += part2[(ch*2)*4 + c]; Q += part2[(ch*2+1)*4 + c]; }
    float mu  = S * (1.0f/BATCH);
    float var = Q * (1.0f/BATCH) - mu*mu;
    float a = g2[ch] * rsqrtf(var + EPS);
    aL[t] = a; cL[t] = beta2[ch] - a*mu;
  }
  __syncthreads();
  const int b = bc*64 + lane;
  const int jb = wv*4;
  float acc[4];
  #pragma unroll
  for (int j=0;j<4;++j) acc[j] = b3[q*32 + jb + j];
  for (int c2=0;c2<8;++c2){
    const h16* src = H2 + ((size_t)(q*8+c2)*BATCH + b)*24;
    float xn[24];
    #pragma unroll
    for (int t=0;t<3;++t){
      H8 u; u.f4 = *reinterpret_cast<const float4*>(src + t*8);
      #pragma unroll
      for (int i=0;i<8;++i){
        int ci = c2*24 + t*8 + i;
        xn[t*8+i] = fmaf(aL[ci], __half2float(u.h[i]), cL[ci]);
      }
    }
    #pragma unroll
    for (int j=0;j<4;++j){
      const float* wr = W3 + q*6144 + (jb+j)*192 + c2*24;
      #pragma unroll
      for (int i=0;i<24;++i) acc[j] = fmaf(xn[i], wr[i], acc[j]);
    }
  }
  #pragma unroll
  for (int j=0;j<4;++j) acc[j] = tanh_fast(acc[j]);
  {
    h16* dst = H3 + (size_t)b*256 + q*32 + jb;
    H2U u0,u1;
    u0.h2 = __halves2half2(__float2half(acc[0]), __float2half(acc[1]));
    u1.h2 = __halves2half2(__float2half(acc[2]), __float2half(acc[3]));
    float2 vv; vv.x = u0.f; vv.y = u1.f;
    *reinterpret_cast<float2*>(dst) = vv;
  }
  #pragma unroll
  for (int j=0;j<4;++j){
    float S = wred(acc[j]);
    float Q = wred(acc[j]*acc[j]);
    if (lane==0){
      part3[((q*32+jb+j)*2  )*64 + bc] = S;
      part3[((q*32+jb+j)*2+1)*64 + bc] = Q;
    }
  }
}

// ---------------- pass D: inline-BN(level3) + root -> Hr f32 [b][64] + stats ----------------
// grid (64 bc, 8 jg), block 256 = 4 waves; wave wv handles channels [wv*64, wv*64+64); LDS combine
__global__ __launch_bounds__(256) void k_passD(const h16* __restrict__ H3, const float* __restrict__ part3,
    const float* __restrict__ g3, const float* __restrict__ beta3,
    const float* __restrict__ Wr, const float* __restrict__ br,
    float* __restrict__ Hr, float* __restrict__ partR){
  const int bc = blockIdx.x;           // 64
  const int jb = blockIdx.y * 8;       // 8 groups
  const int tid = threadIdx.x;
  const int wv = tid >> 6;
  const int lane = tid & 63;
  __shared__ float aL[256], cL[256];
  __shared__ float lacc[4][64][9];
  {
    float S=0.f, Q=0.f;
    for (int c=0;c<64;++c){ S += part3[(tid*2)*64 + c]; Q += part3[(tid*2+1)*64 + c]; }
    float mu  = S * (1.0f/BATCH);
    float var = Q * (1.0f/BATCH) - mu*mu;
    float a = g3[tid] * rsqrtf(var + EPS);
    aL[tid] = a; cL[tid] = beta3[tid] - a*mu;
  }
  __syncthreads();
  const int b = bc*64 + lane;
  float acc[8];
  #pragma unroll
  for (int j=0;j<8;++j) acc[j] = 0.f;
  const h16* src = H3 + (size_t)b*256 + wv*64;
  #pragma unroll
  for (int kk=0; kk<8; ++kk){
    const int sl = wv*8 + kk;
    H8 u; u.f4 = *reinterpret_cast<const float4*>(src + kk*8);
    float xn[8];
    #pragma unroll
    for (int i=0;i<8;++i){
      int ci = sl*8+i;
      xn[i] = fmaf(aL[ci], __half2float(u.h[i]), cL[ci]);
    }
    #pragma unroll
    for (int j=0;j<8;++j){
      const float* wr = Wr + (jb+j)*256 + sl*8;
      #pragma unroll
      for (int i=0;i<8;++i) acc[j] = fmaf(xn[i], wr[i], acc[j]);
    }
  }
  #pragma unroll
  for (int j=0;j<8;++j) lacc[wv][lane][j] = acc[j];
  __syncthreads();
  #pragma unroll
  for (int k=0;k<2;++k){
    const int j = k*4 + wv;
    float v = br[jb+j] + (lacc[0][lane][j] + lacc[1][lane][j]) + (lacc[2][lane][j] + lacc[3][lane][j]);
    v = tanh_fast(v);
    Hr[(size_t)b*64 + jb + j] = v;
    float S = wred(v);
    float Q = wred(v*v);
    if (lane==0){
      partR[((jb+j)*2  )*64 + bc] = S;
      partR[((jb+j)*2+1)*64 + bc] = Q;
    }
  }
}

// ---------------- final BN on root output ----------------
__global__ __launch_bounds__(256) void k_final(const float* __restrict__ Hr, const float* __restrict__ partR,
    const float* __restrict__ gr, const float* __restrict__ betar, float* __restrict__ out){
  __shared__ float aL[64], cL[64];
  const int tid = threadIdx.x;
  if (tid < 64){
    float S=0.f, Q=0.f;
    for (int bc=0; bc<64; ++bc){ S += partR[(tid*2)*64 + bc]; Q += partR[(tid*2+1)*64 + bc]; }
    float mu  = S * (1.0f/BATCH);
    float var = Q * (1.0f/BATCH) - mu*mu;
    float a = gr[tid] * rsqrtf(var + EPS);
    aL[tid] = a; cL[tid] = betar[tid] - a*mu;
  }
  __syncthreads();
  const int i4 = blockIdx.x*256 + tid;       // 65536 float4s
  float4 v = *reinterpret_cast<const float4*>(Hr + (size_t)i4*4);
  int o = (i4*4)&63;
  float4 r;
  r.x = aL[o  ]*v.x + cL[o  ];
  r.y = aL[o+1]*v.y + cL[o+1];
  r.z = aL[o+2]*v.z + cL[o+2];
  r.w = aL[o+3]*v.w + cL[o+3];
  *reinterpret_cast<float4*>(out + (size_t)i4*4) = r;
}

extern "C" void kernel_launch(void* const* d_in, const int* in_sizes, int n_in,
                              void* d_out, int out_size, void* d_ws, size_t ws_size,
                              hipStream_t stream) {
  const float* ms    = (const float*)d_in[0];
  const int*   gidx  = (const int*)  d_in[1];
  const float* W1    = (const float*)d_in[2];
  const float* b1    = (const float*)d_in[3];
  const float* g1    = (const float*)d_in[4];
  const float* beta1 = (const float*)d_in[5];
  const float* W2    = (const float*)d_in[6];
  const float* b2    = (const float*)d_in[7];
  const float* g2    = (const float*)d_in[8];
  const float* beta2 = (const float*)d_in[9];
  const float* W3    = (const float*)d_in[10];
  const float* b3    = (const float*)d_in[11];
  const float* g3    = (const float*)d_in[12];
  const float* beta3 = (const float*)d_in[13];
  const float* Wr    = (const float*)d_in[14];
  const float* br    = (const float*)d_in[15];
  const float* gr    = (const float*)d_in[16];
  const float* betar = (const float*)d_in[17];
  float* out = (float*)d_out;

  char* w = (char*)d_ws;
  size_t off = 0;
  auto take = [&](size_t bytes)->char*{
    char* p = w + off;
    off = (off + bytes + 255) & ~(size_t)255;
    return p;
  };
  h16*   msT    = (h16*)  take((size_t)6000*BATCH*2);
  u32*   H1p    = (u32*)  take((size_t)5120*BATCH*4);
  h16*   H2     = (h16*)  take((size_t)64*BATCH*24*2);
  h16*   H3     = (h16*)  take((size_t)BATCH*256*2);
  float* Hr     = (float*)take((size_t)BATCH*64*4);
  float* part1  = (float*)take((size_t)10240*2*8*4);
  float* part2  = (float*)take((size_t)1536*2*4*4);
  float* part3  = (float*)take((size_t)256*2*64*4);
  float* partR  = (float*)take((size_t)64*2*64*4);
  u32*   W2h    = (u32*)  take((size_t)64*1920*4);
  float* b2f    = (float*)take((size_t)64*24*4);
  if (off > ws_size) return;

  k_transpose<<<dim3(94,64), 256, 0, stream>>>(ms, msT);
  k_statsA<<<dim3(8,512), 64, 0, stream>>>(msT, gidx, W1, b1, H1p, part1);
  k_fold2<<<64, 256, 0, stream>>>(W2, b2, g1, beta1, part1, W2h, b2f);
  k_passB<<<dim3(8,64), 512, 0, stream>>>(H1p, W2h, b2f, H2);
  k_stats2<<<dim3(4,64), 256, 0, stream>>>(H2, part2);
  k_passC<<<dim3(64,8), 512, 0, stream>>>(H2, part2, g2, beta2, W3, b3, H3, part3);
  k_passD<<<dim3(64,8), 256, 0, stream>>>(H3, part3, g3, beta3, Wr, br, Hr, partR);
  k_final<<<256, 256, 0, stream>>>(Hr, partR, gr, betar, out);
}

// Round 14
// 155.857 us; speedup vs baseline: 1.2608x; 1.1634x over previous
//
#include <hip/hip_runtime.h>
#include <hip/hip_fp16.h>

#define BATCH 4096
#define EPS 1e-5f

typedef __half h16;
typedef float f32x2 __attribute__((ext_vector_type(2)));
typedef float f32x4 __attribute__((ext_vector_type(4)));
typedef _Float16 half8 __attribute__((ext_vector_type(8)));
typedef unsigned int u32;

union H8 { float4 f4; h16 h[8]; __half2 h2[4]; };
union U4 { float4 f4; u32 u[4]; };
union H2U { float f; __half2 h2; u32 u; };
union FRU { uint4 q; half8 h; };

__device__ __forceinline__ float tanh_fast(float x){
  float e = __expf(2.0f*x);
  return 1.0f - 2.0f*__builtin_amdgcn_rcpf(e + 1.0f);
}

__device__ __forceinline__ float wred(float v){
  #pragma unroll
  for (int off=32; off; off>>=1) v += __shfl_xor(v, off);
  return v;
}

// ---------------- transpose: ms[4096][6000] f32 -> msT[6000][4096] f16 ----------------
__global__ __launch_bounds__(256) void k_transpose(const float* __restrict__ ms, h16* __restrict__ msT){
  __shared__ float tile[64][65];
  int tc = blockIdx.x * 64;
  int tb = blockIdx.y * 64;
  int tx = threadIdx.x & 63;
  int ty = threadIdx.x >> 6;
  #pragma unroll
  for (int k=0;k<16;++k){
    int r = ty + k*4;
    int c = tc + tx;
    if (c < 6000) tile[r][tx] = ms[(size_t)(tb + r)*6000 + c];
  }
  __syncthreads();
  #pragma unroll
  for (int k=0;k<16;++k){
    int r = ty + k*4;
    int c = tc + r;
    if (c < 6000) msT[(size_t)c*BATCH + tb + tx] = __float2half(tile[tx][r]);
  }
}

// ---------------- pass A: level-1 linear+tanh -> H1p[pair][b] u32 + stats ----------------
// grid (8 bc, 512 s), block 64; thread handles 8 batch elems
__global__ __launch_bounds__(64,2) void k_statsA(const h16* __restrict__ msT, const int* __restrict__ gidx,
    const float* __restrict__ W1, const float* __restrict__ b1,
    u32* __restrict__ H1p, float* __restrict__ part1){
  const int s = blockIdx.y;
  const int bc = blockIdx.x;           // 8
  const int lane = threadIdx.x;
  const int b0 = bc*512 + lane*8;
  const float* Wp = W1 + s*320;
  f32x2 acc[20][4];
  #pragma unroll
  for (int o=0;o<20;++o){
    float bv = b1[s*20+o];
    #pragma unroll
    for (int k=0;k<4;++k) acc[o][k] = (f32x2){bv,bv};
  }
  #pragma unroll 4
  for (int g=0; g<16; ++g){
    const int row = gidx[s*16+g]*BATCH;        // s block-uniform -> SGPR
    H8 u; u.f4 = *reinterpret_cast<const float4*>(msT + row + b0);
    f32x2 x[4];
    #pragma unroll
    for (int k=0;k<4;++k){
      float2 f = __half22float2(u.h2[k]);
      x[k] = (f32x2){f.x, f.y};
    }
    #pragma unroll
    for (int o=0;o<20;++o){
      float wv = Wp[o*16+g];
      f32x2 w2 = (f32x2){wv,wv};
      #pragma unroll
      for (int k=0;k<4;++k) acc[o][k] = __builtin_elementwise_fma(x[k], w2, acc[o][k]);
    }
  }
  #pragma unroll
  for (int op=0;op<10;++op){
    const int oA = 2*op, oB = 2*op+1;
    float hA[8], hB[8];
    #pragma unroll
    for (int k=0;k<4;++k){
      hA[2*k]   = tanh_fast(acc[oA][k].x);
      hA[2*k+1] = tanh_fast(acc[oA][k].y);
      hB[2*k]   = tanh_fast(acc[oB][k].x);
      hB[2*k+1] = tanh_fast(acc[oB][k].y);
    }
    U4 v0, v1;
    #pragma unroll
    for (int k=0;k<4;++k){
      H2U a; a.h2 = __halves2half2(__float2half(hA[k]),   __float2half(hB[k]));   v0.u[k] = a.u;
      H2U b; b.h2 = __halves2half2(__float2half(hA[k+4]), __float2half(hB[k+4])); v1.u[k] = b.u;
    }
    u32* dst = H1p + (size_t)(s*10+op)*BATCH + b0;
    *reinterpret_cast<float4*>(dst)     = v0.f4;
    *reinterpret_cast<float4*>(dst + 4) = v1.f4;
    float SA = ((hA[0]+hA[1])+(hA[2]+hA[3])) + ((hA[4]+hA[5])+(hA[6]+hA[7]));
    float QA = ((hA[0]*hA[0]+hA[1]*hA[1])+(hA[2]*hA[2]+hA[3]*hA[3]))
             + ((hA[4]*hA[4]+hA[5]*hA[5])+(hA[6]*hA[6]+hA[7]*hA[7]));
    float SB = ((hB[0]+hB[1])+(hB[2]+hB[3])) + ((hB[4]+hB[5])+(hB[6]+hB[7]));
    float QB = ((hB[0]*hB[0]+hB[1]*hB[1])+(hB[2]*hB[2]+hB[3]*hB[3]))
             + ((hB[4]*hB[4]+hB[5]*hB[5])+(hB[6]*hB[6]+hB[7]*hB[7]));
    SA = wred(SA); QA = wred(QA); SB = wred(SB); QB = wred(QB);
    if (lane==0){
      part1[((s*20+oA)*2  )*8 + bc] = SA;
      part1[((s*20+oA)*2+1)*8 + bc] = QA;
      part1[((s*20+oB)*2  )*8 + bc] = SB;
      part1[((s*20+oB)*2+1)*8 + bc] = QB;
    }
  }
}

// ---------------- fold level-1 BN into W2 -> MFMA A-fragments ----------------
// Wfrag[p][f=jt*5+kc][lane][8 f16]: A row j = jt*16+(lane&15), k = kc*32+(lane>>4)*8+e
__global__ __launch_bounds__(256) void k_fold2(const float* __restrict__ W, const float* __restrict__ bb,
    const float* __restrict__ g, const float* __restrict__ beta,
    const float* __restrict__ part, uint4* __restrict__ Wfrag, float* __restrict__ bf){
  const int p = blockIdx.x;
  const int tid = threadIdx.x;
  __shared__ float aL[160], cL[160];
  for (int t = tid; t < 160; t += 256){
    int ch = p*160 + t;
    float S=0.f, Q=0.f;
    for (int bc=0; bc<8; ++bc){ S += part[(ch*2)*8 + bc]; Q += part[(ch*2+1)*8 + bc]; }
    float mu  = S * (1.0f/BATCH);
    float var = Q * (1.0f/BATCH) - mu*mu;
    float a = g[ch] * rsqrtf(var + EPS);
    aL[t] = a;
    cL[t] = beta[ch] - a*mu;
  }
  __syncthreads();
  for (int E = tid; E < 640; E += 256){
    int f = E >> 6, l = E & 63;
    int jt = f/5, kc = f%5;
    int j = jt*16 + (l&15);
    int gg = l>>4;
    u32 q[4];
    #pragma unroll
    for (int e2=0; e2<4; ++e2){
      int i0 = kc*32 + gg*8 + 2*e2;
      float w0=0.f, w1=0.f;
      if (j < 24){
        w0 = W[p*3840 + j*160 + i0    ] * aL[i0];
        w1 = W[p*3840 + j*160 + i0 + 1] * aL[i0+1];
      }
      H2U u; u.h2 = __halves2half2(__float2half(w0), __float2half(w1));
      q[e2] = u.u;
    }
    Wfrag[p*640 + E] = make_uint4(q[0],q[1],q[2],q[3]);
  }
  if (tid < 24){
    float sv = bb[p*24 + tid];
    for (int i=0;i<160;++i) sv = fmaf(W[p*3840 + tid*160 + i], cL[i], sv);
    bf[p*24 + tid] = sv;
  }
}

// ---------------- pass B (MFMA): H2[p][b][24] = tanh(W2f x H1 + b2f) ----------------
// grid (16 bc, 64 p), block 256 = 4 waves; per iter stage 64 batch x 160 ch into LDS
__global__ __launch_bounds__(256) void k_passB(const u32* __restrict__ H1p,
    const uint4* __restrict__ Wfrag, const float* __restrict__ b2f,
    h16* __restrict__ H2){
  const int p = blockIdx.y;
  const int bc = blockIdx.x;           // 16
  const int tid = threadIdx.x;
  const int wv = tid >> 6;
  const int l = tid & 63;
  const int g = l >> 4;
  __shared__ u32 lds[64*84];           // [batch 64][pair-row 80 + pad4], 16B-aligned rows
  half8 wf[10];
  #pragma unroll
  for (int f=0; f<10; ++f){
    FRU u; u.q = Wfrag[p*640 + f*64 + l];
    wf[f] = u.h;
  }
  const u32* __restrict__ hp = H1p + (size_t)p*80*BATCH;
  const float* bp = b2f + p*24;
  float bj0[4], bj1[4];
  #pragma unroll
  for (int r=0;r<4;++r){
    bj0[r] = bp[g*4+r];
    bj1[r] = (g<2) ? bp[16+g*4+r] : 0.f;
  }
  for (int it=0; it<4; ++it){
    const int b0 = bc*256 + it*64;
    __syncthreads();
    #pragma unroll
    for (int rr=0; rr<20; ++rr){
      int r = rr*4 + wv;
      lds[l*84 + r] = hp[(size_t)r*BATCH + b0 + l];
    }
    __syncthreads();
    const int bb = wv*16 + (l&15);
    f32x4 acc0 = {0.f,0.f,0.f,0.f}, acc1 = {0.f,0.f,0.f,0.f};
    #pragma unroll
    for (int kc=0; kc<5; ++kc){
      FRU u; u.q = *reinterpret_cast<const uint4*>(&lds[bb*84 + kc*16 + g*4]);
      acc0 = __builtin_amdgcn_mfma_f32_16x16x32_f16(wf[kc],   u.h, acc0, 0,0,0);
      acc1 = __builtin_amdgcn_mfma_f32_16x16x32_f16(wf[5+kc], u.h, acc1, 0,0,0);
    }
    const int B = b0 + bb;
    h16* dst = H2 + ((size_t)p*BATCH + B)*24;
    {
      H2U u0,u1;
      u0.h2 = __halves2half2(__float2half(tanh_fast(acc0[0]+bj0[0])), __float2half(tanh_fast(acc0[1]+bj0[1])));
      u1.h2 = __halves2half2(__float2half(tanh_fast(acc0[2]+bj0[2])), __float2half(tanh_fast(acc0[3]+bj0[3])));
      *reinterpret_cast<uint2*>(dst + g*4) = make_uint2(u0.u, u1.u);
    }
    if (g < 2){
      H2U u0,u1;
      u0.h2 = __halves2half2(__float2half(tanh_fast(acc1[0]+bj1[0])), __float2half(tanh_fast(acc1[1]+bj1[1])));
      u1.h2 = __halves2half2(__float2half(tanh_fast(acc1[2]+bj1[2])), __float2half(tanh_fast(acc1[3]+bj1[3])));
      *reinterpret_cast<uint2*>(dst + 16 + g*4) = make_uint2(u0.u, u1.u);
    }
  }
}

// ---------------- stats over H2 -> part2 [ch*2+{0,1}][4 chunks] ----------------
// grid (4 bc, 64 p), block 256; thread accumulates 4 rows of 24 ch
__global__ __launch_bounds__(256) void k_stats2(const h16* __restrict__ H2, float* __restrict__ part2){
  const int p = blockIdx.y;
  const int bc = blockIdx.x;           // 4
  const int tid = threadIdx.x;
  const int wv = tid >> 6;
  const int lane = tid & 63;
  float S[24], Q[24];
  #pragma unroll
  for (int j=0;j<24;++j){ S[j]=0.f; Q[j]=0.f; }
  const h16* base = H2 + ((size_t)p*BATCH + bc*1024 + tid)*24;
  for (int it=0; it<4; ++it){
    const h16* src = base + (size_t)it*256*24;
    #pragma unroll
    for (int t=0;t<3;++t){
      H8 u; u.f4 = *reinterpret_cast<const float4*>(src + t*8);
      #pragma unroll
      for (int i=0;i<8;++i){
        float v = __half2float(u.h[i]);
        S[t*8+i] += v;
        Q[t*8+i] = fmaf(v, v, Q[t*8+i]);
      }
    }
  }
  __shared__ float red[2][4][24];
  #pragma unroll
  for (int j=0;j<24;++j){
    float s = wred(S[j]);
    float q = wred(Q[j]);
    if (lane==0){ red[0][wv][j] = s; red[1][wv][j] = q; }
  }
  __syncthreads();
  if (tid < 24){
    float s = (red[0][0][tid]+red[0][1][tid]) + (red[0][2][tid]+red[0][3][tid]);
    float q = (red[1][0][tid]+red[1][1][tid]) + (red[1][2][tid]+red[1][3][tid]);
    const int ch = p*24 + tid;
    part2[(ch*2  )*4 + bc] = s;
    part2[(ch*2+1)*4 + bc] = q;
  }
}

// ---------------- pass C: inline-BN(level2) + level-3 -> H3[b][256] + stats ----------------
// grid (64 bc, 8 q), block 512 (8 waves x 4 outputs)
__global__ __launch_bounds__(512) void k_passC(const h16* __restrict__ H2, const float* __restrict__ part2,
    const float* __restrict__ g2, const float* __restrict__ beta2,
    const float* __restrict__ W3, const float* __restrict__ b3,
    h16* __restrict__ H3, float* __restrict__ part3){
  const int q = blockIdx.y;
  const int bc = blockIdx.x;           // 64
  const int tid = threadIdx.x;
  const int wv = tid >> 6;
  const int lane = tid & 63;
  __shared__ float aL[192], cL[192];
  for (int t = tid; t < 192; t += 512){
    int ch = q*192 + t;
    float S=0.f, Q=0.f;
    #pragma unroll
    for (int c=0;c<4;++c){ S += part2[(ch*2)*4 + c]; Q += part2[(ch*2+1)*4 + c]; }
    float mu  = S * (1.0f/BATCH);
    float var = Q * (1.0f/BATCH) - mu*mu;
    float a = g2[ch] * rsqrtf(var + EPS);
    aL[t] = a; cL[t] = beta2[ch] - a*mu;
  }
  __syncthreads();
  const int b = bc*64 + lane;
  const int jb = wv*4;
  float acc[4];
  #pragma unroll
  for (int j=0;j<4;++j) acc[j] = b3[q*32 + jb + j];
  for (int c2=0;c2<8;++c2){
    const h16* src = H2 + ((size_t)(q*8+c2)*BATCH + b)*24;
    float xn[24];
    #pragma unroll
    for (int t=0;t<3;++t){
      H8 u; u.f4 = *reinterpret_cast<const float4*>(src + t*8);
      #pragma unroll
      for (int i=0;i<8;++i){
        int ci = c2*24 + t*8 + i;
        xn[t*8+i] = fmaf(aL[ci], __half2float(u.h[i]), cL[ci]);
      }
    }
    #pragma unroll
    for (int j=0;j<4;++j){
      const float* wr = W3 + q*6144 + (jb+j)*192 + c2*24;
      #pragma unroll
      for (int i=0;i<24;++i) acc[j] = fmaf(xn[i], wr[i], acc[j]);
    }
  }
  #pragma unroll
  for (int j=0;j<4;++j) acc[j] = tanh_fast(acc[j]);
  {
    h16* dst = H3 + (size_t)b*256 + q*32 + jb;
    H2U u0,u1;
    u0.h2 = __halves2half2(__float2half(acc[0]), __float2half(acc[1]));
    u1.h2 = __halves2half2(__float2half(acc[2]), __float2half(acc[3]));
    float2 vv; vv.x = u0.f; vv.y = u1.f;
    *reinterpret_cast<float2*>(dst) = vv;
  }
  #pragma unroll
  for (int j=0;j<4;++j){
    float S = wred(acc[j]);
    float Q = wred(acc[j]*acc[j]);
    if (lane==0){
      part3[((q*32+jb+j)*2  )*64 + bc] = S;
      part3[((q*32+jb+j)*2+1)*64 + bc] = Q;
    }
  }
}

// ---------------- pass D: inline-BN(level3) + root -> Hr f32 [b][64] + stats ----------------
// grid (64 bc, 8 jg), block 256 = 4 waves; wave wv handles channels [wv*64, wv*64+64); LDS combine
__global__ __launch_bounds__(256) void k_passD(const h16* __restrict__ H3, const float* __restrict__ part3,
    const float* __restrict__ g3, const float* __restrict__ beta3,
    const float* __restrict__ Wr, const float* __restrict__ br,
    float* __restrict__ Hr, float* __restrict__ partR){
  const int bc = blockIdx.x;           // 64
  const int jb = blockIdx.y * 8;       // 8 groups
  const int tid = threadIdx.x;
  const int wv = tid >> 6;
  const int lane = tid & 63;
  __shared__ float aL[256], cL[256];
  __shared__ float lacc[4][64][9];
  {
    float S=0.f, Q=0.f;
    for (int c=0;c<64;++c){ S += part3[(tid*2)*64 + c]; Q += part3[(tid*2+1)*64 + c]; }
    float mu  = S * (1.0f/BATCH);
    float var = Q * (1.0f/BATCH) - mu*mu;
    float a = g3[tid] * rsqrtf(var + EPS);
    aL[tid] = a; cL[tid] = beta3[tid] - a*mu;
  }
  __syncthreads();
  const int b = bc*64 + lane;
  float acc[8];
  #pragma unroll
  for (int j=0;j<8;++j) acc[j] = 0.f;
  const h16* src = H3 + (size_t)b*256 + wv*64;
  #pragma unroll
  for (int kk=0; kk<8; ++kk){
    const int sl = wv*8 + kk;
    H8 u; u.f4 = *reinterpret_cast<const float4*>(src + kk*8);
    float xn[8];
    #pragma unroll
    for (int i=0;i<8;++i){
      int ci = sl*8+i;
      xn[i] = fmaf(aL[ci], __half2float(u.h[i]), cL[ci]);
    }
    #pragma unroll
    for (int j=0;j<8;++j){
      const float* wr = Wr + (jb+j)*256 + sl*8;
      #pragma unroll
      for (int i=0;i<8;++i) acc[j] = fmaf(xn[i], wr[i], acc[j]);
    }
  }
  #pragma unroll
  for (int j=0;j<8;++j) lacc[wv][lane][j] = acc[j];
  __syncthreads();
  #pragma unroll
  for (int k=0;k<2;++k){
    const int j = k*4 + wv;
    float v = br[jb+j] + (lacc[0][lane][j] + lacc[1][lane][j]) + (lacc[2][lane][j] + lacc[3][lane][j]);
    v = tanh_fast(v);
    Hr[(size_t)b*64 + jb + j] = v;
    float S = wred(v);
    float Q = wred(v*v);
    if (lane==0){
      partR[((jb+j)*2  )*64 + bc] = S;
      partR[((jb+j)*2+1)*64 + bc] = Q;
    }
  }
}

// ---------------- final BN on root output ----------------
__global__ __launch_bounds__(256) void k_final(const float* __restrict__ Hr, const float* __restrict__ partR,
    const float* __restrict__ gr, const float* __restrict__ betar, float* __restrict__ out){
  __shared__ float aL[64], cL[64];
  const int tid = threadIdx.x;
  if (tid < 64){
    float S=0.f, Q=0.f;
    for (int bc=0; bc<64; ++bc){ S += partR[(tid*2)*64 + bc]; Q += partR[(tid*2+1)*64 + bc]; }
    float mu  = S * (1.0f/BATCH);
    float var = Q * (1.0f/BATCH) - mu*mu;
    float a = gr[tid] * rsqrtf(var + EPS);
    aL[tid] = a; cL[tid] = betar[tid] - a*mu;
  }
  __syncthreads();
  const int i4 = blockIdx.x*256 + tid;       // 65536 float4s
  float4 v = *reinterpret_cast<const float4*>(Hr + (size_t)i4*4);
  int o = (i4*4)&63;
  float4 r;
  r.x = aL[o  ]*v.x + cL[o  ];
  r.y = aL[o+1]*v.y + cL[o+1];
  r.z = aL[o+2]*v.z + cL[o+2];
  r.w = aL[o+3]*v.w + cL[o+3];
  *reinterpret_cast<float4*>(out + (size_t)i4*4) = r;
}

extern "C" void kernel_launch(void* const* d_in, const int* in_sizes, int n_in,
                              void* d_out, int out_size, void* d_ws, size_t ws_size,
                              hipStream_t stream) {
  const float* ms    = (const float*)d_in[0];
  const int*   gidx  = (const int*)  d_in[1];
  const float* W1    = (const float*)d_in[2];
  const float* b1    = (const float*)d_in[3];
  const float* g1    = (const float*)d_in[4];
  const float* beta1 = (const float*)d_in[5];
  const float* W2    = (const float*)d_in[6];
  const float* b2    = (const float*)d_in[7];
  const float* g2    = (const float*)d_in[8];
  const float* beta2 = (const float*)d_in[9];
  const float* W3    = (const float*)d_in[10];
  const float* b3    = (const float*)d_in[11];
  const float* g3    = (const float*)d_in[12];
  const float* beta3 = (const float*)d_in[13];
  const float* Wr    = (const float*)d_in[14];
  const float* br    = (const float*)d_in[15];
  const float* gr    = (const float*)d_in[16];
  const float* betar = (const float*)d_in[17];
  float* out = (float*)d_out;

  char* w = (char*)d_ws;
  size_t off = 0;
  auto take = [&](size_t bytes)->char*{
    char* p = w + off;
    off = (off + bytes + 255) & ~(size_t)255;
    return p;
  };
  h16*   msT    = (h16*)  take((size_t)6000*BATCH*2);
  u32*   H1p    = (u32*)  take((size_t)5120*BATCH*4);
  h16*   H2     = (h16*)  take((size_t)64*BATCH*24*2);
  h16*   H3     = (h16*)  take((size_t)BATCH*256*2);
  float* Hr     = (float*)take((size_t)BATCH*64*4);
  float* part1  = (float*)take((size_t)10240*2*8*4);
  float* part2  = (float*)take((size_t)1536*2*4*4);
  float* part3  = (float*)take((size_t)256*2*64*4);
  float* partR  = (float*)take((size_t)64*2*64*4);
  uint4* Wfrag  = (uint4*)take((size_t)64*640*16);
  float* b2f    = (float*)take((size_t)64*24*4);
  if (off > ws_size) return;

  k_transpose<<<dim3(94,64), 256, 0, stream>>>(ms, msT);
  k_statsA<<<dim3(8,512), 64, 0, stream>>>(msT, gidx, W1, b1, H1p, part1);
  k_fold2<<<64, 256, 0, stream>>>(W2, b2, g1, beta1, part1, Wfrag, b2f);
  k_passB<<<dim3(16,64), 256, 0, stream>>>(H1p, Wfrag, b2f, H2);
  k_stats2<<<dim3(4,64), 256, 0, stream>>>(H2, part2);
  k_passC<<<dim3(64,8), 512, 0, stream>>>(H2, part2, g2, beta2, W3, b3, H3, part3);
  k_passD<<<dim3(64,8), 256, 0, stream>>>(H3, part3, g3, beta3, Wr, br, Hr, partR);
  k_final<<<256, 256, 0, stream>>>(Hr, partR, gr, betar, out);
}